// Round 26
// baseline (231.226 us; speedup 1.0000x reference)
//
#include <hip/hip_runtime.h>
#include <hip/hip_bf16.h>
#include <cmath>

#define B_   2
#define S_   2048
#define D_   1024
#define H_   16
#define DFF_ 4096
#define DH_  64
#define M_   (B_*S_)   // 4096 rows

typedef __bf16 bfx8 __attribute__((ext_vector_type(8)));
typedef __bf16 bfx4 __attribute__((ext_vector_type(4)));
typedef float  fx4  __attribute__((ext_vector_type(4)));

__device__ __forceinline__ float fast_exp2(float x) {
  float r;
  asm volatile("v_exp_f32 %0, %1" : "=v"(r) : "v"(x));
  return r;
}

// Abramowitz-Stegun 7.1.26 erf (max abs err 1.5e-7; exact at bf16 granularity)
__device__ __forceinline__ float fast_erf(float x) {
  float ax = fabsf(x);
  float t  = __builtin_amdgcn_rcpf(fmaf(0.3275911f, ax, 1.0f));
  float p  = fmaf(1.061405429f, t, -1.453152027f);
  p = fmaf(p, t, 1.421413741f);
  p = fmaf(p, t, -0.284496736f);
  p = fmaf(p, t, 0.254829592f);
  p = p * t;
  float e  = fast_exp2(-ax * ax * 1.44269504f);
  float r  = 1.0f - p * e;
  return copysignf(r, x);
}

// ---------------------------------------------------------------- utilities
__device__ __forceinline__ void gload_lds16(const void* g, void* l) {
  __builtin_amdgcn_global_load_lds((__attribute__((address_space(1))) void*)(g),
                                   (__attribute__((address_space(3))) void*)(l),
                                   16, 0, 0);
}

// --- combined preprocessing: 6 weight transposes + 3 fp32->bf16 + mask scale
struct PrepArgs {
  const float* win[6]; __bf16* wout[6];
  const float* cin[3]; __bf16* cout[3];
  const float* min;    float* mout;     // mask * log2(e) -> global f32
};

__global__ __launch_bounds__(256)
void prep_kernel(PrepArgs a) {
  int bid = blockIdx.x;
  if (bid < 12288) {
    __shared__ float t[32][33];
    int wsel, tr, tc, R, C;
    if (bid < 4096) {
      wsel = bid >> 10; int l = bid & 1023;
      tr = l >> 5; tc = l & 31; R = D_; C = D_;
    } else if (bid < 8192) {
      wsel = 4; int l = bid - 4096;
      tr = l >> 7; tc = l & 127; R = D_; C = DFF_;
    } else {
      wsel = 5; int l = bid - 8192;
      tr = l >> 5; tc = l & 31; R = DFF_; C = D_;
    }
    const float* in = a.win[wsel];
    __bf16* out = a.wout[wsel];
    int r0 = tr * 32, c0 = tc * 32;
    int tx = threadIdx.x & 31, ty = threadIdx.x >> 5;   // 32 x 8
#pragma unroll
    for (int j = 0; j < 4; ++j) {
      int r = ty + j * 8;
      t[r][tx] = in[(size_t)(r0 + r) * C + c0 + tx];
    }
    __syncthreads();
#pragma unroll
    for (int j = 0; j < 4; ++j) {
      int c = ty + j * 8;
      out[(size_t)(c0 + c) * R + r0 + tx] = (__bf16)t[tx][c];
    }
  } else if (bid < 24576) {
    int l = bid - 12288;
    int z = l >> 12;                      // 0..2
    int i = ((l & 4095) * 256 + threadIdx.x) * 4;
    float4 v = *(const float4*)(a.cin[z] + i);
    bfx4 o;
    o[0] = (__bf16)v.x; o[1] = (__bf16)v.y; o[2] = (__bf16)v.z; o[3] = (__bf16)v.w;
    *(bfx4*)(a.cout[z] + i) = o;
  } else {
    int i = ((bid - 24576) * 256 + threadIdx.x) * 4;  // 4 blocks x 1024 = 4096
    float4 v = *(const float4*)(a.min + i);
    v.x *= 1.44269504f; v.y *= 1.44269504f;
    v.z *= 1.44269504f; v.w *= 1.44269504f;
    *(float4*)(a.mout + i) = v;
  }
}

// --------------------------------------------------------------- GEMM tile
// Double-buffered, counted-vmcnt; BM/TBN templated.
// MODE 0: bf16 out. 1: f32 out. 2: GELU bf16. 4: bf16 + bf16 residual.
// MODE 5: bf16 stored transposed into vt[B,H,DH,S] (4 consecutive s).
template<int MODE, int BM, int TBN>
__device__ __forceinline__ void gemm_body(const __bf16* __restrict__ A,
                                          const __bf16* __restrict__ Bt,
                                          const float* __restrict__ bias,
                                          const void* __restrict__ res,
                                          void* __restrict__ out,
                                          int Ndim, int Kdim, int m0, int n0,
                                          __bf16* As, __bf16* Bs) {
  const int tid  = threadIdx.x;
  const int lane = tid & 63;
  const int w    = tid >> 6;
  const int wm   = w >> 1, wn = w & 1;
  constexpr int MF = BM / 32;
  constexpr int NF = TBN / 32;
  constexpr int AL = BM / 32;
  constexpr int BL = TBN / 32;
  constexpr int VM = AL + BL;

  fx4 acc[MF][NF];
#pragma unroll
  for (int i = 0; i < MF; ++i)
#pragma unroll
    for (int j = 0; j < NF; ++j) acc[i][j] = {0.f, 0.f, 0.f, 0.f};

  const int KT = Kdim / 64;

  auto stage = [&](int kt, int buf) {
    const int kb0 = kt * 64;
#pragma unroll
    for (int i = 0; i < AL; ++i) {
      int o   = tid * 16 + i * 4096;
      int row = o >> 7, cb = o & 127;
      int cbs = cb ^ ((row & 7) << 4);
      gload_lds16((const char*)A + ((size_t)(m0 + row) * Kdim + kb0) * 2 + cbs,
                  (char*)As + buf * (BM * 128) + o);
    }
#pragma unroll
    for (int i = 0; i < BL; ++i) {
      int o   = tid * 16 + i * 4096;
      int row = o >> 7, cb = o & 127;
      int cbs = cb ^ ((row & 7) << 4);
      gload_lds16((const char*)Bt + ((size_t)(n0 + row) * Kdim + kb0) * 2 + cbs,
                  (char*)Bs + buf * (TBN * 128) + o);
    }
  };

  stage(0, 0);
  asm volatile("s_waitcnt vmcnt(0)" ::: "memory");
  __builtin_amdgcn_s_barrier();
  __builtin_amdgcn_sched_barrier(0);

  for (int kt = 0; kt < KT; ++kt) {
    if (kt + 1 < KT) stage(kt + 1, (kt + 1) & 1);
    __builtin_amdgcn_sched_barrier(0);
    if (kt > 0) {
      if (kt + 1 < KT) {
        if constexpr (VM == 4)      asm volatile("s_waitcnt vmcnt(4)" ::: "memory");
        else if constexpr (VM == 6) asm volatile("s_waitcnt vmcnt(6)" ::: "memory");
        else                        asm volatile("s_waitcnt vmcnt(8)" ::: "memory");
      } else {
        asm volatile("s_waitcnt vmcnt(0)" ::: "memory");
      }
      __builtin_amdgcn_s_barrier();
      __builtin_amdgcn_sched_barrier(0);
    }
    const char* Ab = (const char*)As + (kt & 1) * (BM * 128);
    const char* Bb = (const char*)Bs + (kt & 1) * (TBN * 128);

#pragma unroll
    for (int kk = 0; kk < 2; ++kk) {
      bfx8 afr[MF], bfr[NF];
      const int cb = kk * 64 + ((lane >> 4) << 4);
#pragma unroll
      for (int mf = 0; mf < MF; ++mf) {
        int row = wm * (BM / 2) + mf * 16 + (lane & 15);
        afr[mf] = *(const bfx8*)(Ab + row * 128 + (cb ^ ((row & 7) << 4)));
      }
#pragma unroll
      for (int nf = 0; nf < NF; ++nf) {
        int row = wn * (TBN / 2) + nf * 16 + (lane & 15);
        bfr[nf] = *(const bfx8*)(Bb + row * 128 + (cb ^ ((row & 7) << 4)));
      }
#pragma unroll
      for (int mf = 0; mf < MF; ++mf)
#pragma unroll
        for (int nf = 0; nf < NF; ++nf)
          acc[mf][nf] = __builtin_amdgcn_mfma_f32_16x16x32_bf16(afr[mf], bfr[nf],
                                                                acc[mf][nf], 0, 0, 0);
    }
    __builtin_amdgcn_s_barrier();
    __builtin_amdgcn_sched_barrier(0);
  }

#pragma unroll
  for (int mf = 0; mf < MF; ++mf) {
#pragma unroll
    for (int nf = 0; nf < NF; ++nf) {
      int col = n0 + wn * (TBN / 2) + nf * 16 + (lane & 15);
      float bvl = bias[col];
      if (MODE == 5) {
        int rowg0 = m0 + wm * (BM / 2) + mf * 16 + ((lane >> 4) << 2);
        int bb = rowg0 >> 11, s = rowg0 & 2047;        // S_=2048
        int hh = col >> 6, dh = col & 63;
        bfx4 o;
#pragma unroll
        for (int r = 0; r < 4; ++r) o[r] = (__bf16)(acc[mf][nf][r] + bvl);
        *(bfx4*)((__bf16*)out + (((size_t)(bb * 16 + hh) * 64 + dh) * 2048 + s)) = o;
      } else {
#pragma unroll
        for (int r = 0; r < 4; ++r) {
          int rowg = m0 + wm * (BM / 2) + mf * 16 + ((lane >> 4) << 2) + r;
          float v = acc[mf][nf][r] + bvl;
          if (MODE == 2) v = 0.5f * v * (1.0f + fast_erf(v * 0.70710678118654752f));
          if (MODE == 4) v += (float)((const __bf16*)res)[(size_t)rowg * Ndim + col];
          if (MODE == 1) ((float*)out)[(size_t)rowg * Ndim + col] = v;
          else           ((__bf16*)out)[(size_t)rowg * Ndim + col] = (__bf16)v;
        }
      }
    }
  }
}

template<int MODE, int BM, int TBN>
__global__ __launch_bounds__(256)
void gemm_kernel(const __bf16* __restrict__ A, const __bf16* __restrict__ Bt,
                 const float* __restrict__ bias, const void* __restrict__ res,
                 void* __restrict__ out, int Ndim, int Kdim) {
  __shared__ alignas(16) __bf16 As[2 * BM * 64];
  __shared__ alignas(16) __bf16 Bs[2 * TBN * 64];
  const int gX  = gridDim.x;
  const int nwg = gridDim.x * gridDim.y;
  int lid = blockIdx.y * gX + blockIdx.x;
  int swz = (lid & 7) * (nwg >> 3) + (lid >> 3);
  gemm_body<MODE, BM, TBN>(A, Bt, bias, res, out, Ndim, Kdim,
                           (swz / gX) * BM, (swz % gX) * TBN, As, Bs);
}

struct QKVArgs {
  const __bf16* A[3]; const __bf16* Bt[3]; const float* bias[3]; __bf16* out[3];
};

// THIS ROUND: QKV on the 128x128 dbuf structure; per-plane grid (8,32)=256
// blocks, x3 planes = 768 blocks (3/CU grid-wise; LDS 64 KB -> 2 resident).
// V plane (z==2) stores transposed (MODE 5). Per-plane XCD swizzle (256%8==0).
__global__ __launch_bounds__(256)
void qkv128_kernel(QKVArgs args, int Ndim, int Kdim) {
  __shared__ alignas(16) __bf16 As[2 * 128 * 64];
  __shared__ alignas(16) __bf16 Bs[2 * 128 * 64];
  int z = blockIdx.z;
  const int gX  = gridDim.x;                         // 8
  const int nwg = gridDim.x * gridDim.y;             // 256
  int lid = blockIdx.y * gX + blockIdx.x;
  int swz = (lid & 7) * (nwg >> 3) + (lid >> 3);
  int m0 = (swz / gX) * 128, n0 = (swz % gX) * 128;
  if (z == 2)
    gemm_body<5, 128, 128>(args.A[2], args.Bt[2], args.bias[2], nullptr,
                           (void*)args.out[2], Ndim, Kdim, m0, n0, As, Bs);
  else if (z == 1)
    gemm_body<0, 128, 128>(args.A[1], args.Bt[1], args.bias[1], nullptr,
                           (void*)args.out[1], Ndim, Kdim, m0, n0, As, Bs);
  else
    gemm_body<0, 128, 128>(args.A[0], args.Bt[0], args.bias[0], nullptr,
                           (void*)args.out[0], Ndim, Kdim, m0, n0, As, Bs);
}

// --------------------------------------------------------------- GEMM 256-tile
// (round-9 validated 8-phase schedule; used for Wi only)
__device__ __forceinline__ void stage_a256(const __bf16* __restrict__ A, int m0,
                                           int Kdim, int tile, int h, char* Asm) {
  char* dst = Asm + (tile & 1) * 32768;
  const int kb0 = tile * 64;
  const int tid = threadIdx.x;
#pragma unroll
  for (int it = 0; it < 2; ++it) {
    int o = tid * 16 + it * 8192;
    int lrow = o >> 7, cb = o & 127;
    int r = (lrow & 63) + h * 64 + ((lrow >> 6) << 7);
    int csrc = cb ^ ((r & 7) << 4);
    gload_lds16((const char*)A + ((size_t)(m0 + r) * Kdim + kb0) * 2 + csrc,
                dst + r * 128 + cb);
  }
}
__device__ __forceinline__ void stage_b256(const __bf16* __restrict__ Bt, int n0,
                                           int Kdim, int tile, int h, char* Bsm) {
  char* dst = Bsm + (tile & 1) * 32768;
  const int kb0 = tile * 64;
  const int tid = threadIdx.x;
#pragma unroll
  for (int it = 0; it < 2; ++it) {
    int o = tid * 16 + it * 8192;
    int lrow = o >> 7, cb = o & 127;
    int r = h * 128 + lrow;
    int csrc = cb ^ ((r & 7) << 4);
    gload_lds16((const char*)Bt + ((size_t)(n0 + r) * Kdim + kb0) * 2 + csrc,
                dst + r * 128 + cb);
  }
}

template<int MODE>
__device__ __forceinline__ void gemm256_body(const __bf16* __restrict__ A,
                                             const __bf16* __restrict__ Bt,
                                             const float* __restrict__ bias,
                                             void* __restrict__ out,
                                             int Ndim, int Kdim, int m0, int n0) {
  extern __shared__ char smem[];
  char* Asm = smem;
  char* Bsm = smem + 65536;
  const int tid  = threadIdx.x;
  const int lane = tid & 63;
  const int w    = tid >> 6;
  const int wm   = w >> 2;
  const int wn   = w & 3;
  const int g    = lane >> 4;
  const int ql   = lane & 15;
  const int KT   = Kdim / 64;

  fx4 acc[8][4];
#pragma unroll
  for (int i = 0; i < 8; ++i)
#pragma unroll
    for (int j = 0; j < 4; ++j) acc[i][j] = {0.f, 0.f, 0.f, 0.f};

  stage_a256(A, m0, Kdim, 0, 0, Asm);
  stage_a256(A, m0, Kdim, 0, 1, Asm);
  stage_b256(Bt, n0, Kdim, 0, 0, Bsm);
  stage_b256(Bt, n0, Kdim, 0, 1, Bsm);
  stage_a256(A, m0, Kdim, 1, 0, Asm);
  asm volatile("s_waitcnt vmcnt(2)" ::: "memory");
  __builtin_amdgcn_s_barrier();
  __builtin_amdgcn_sched_barrier(0);

  for (int t = 0; t < KT; ++t) {
    const char* Ab = Asm + (t & 1) * 32768;
    const char* Bb = Bsm + (t & 1) * 32768;
#pragma unroll
    for (int p = 0; p < 4; ++p) {
      const int ah = p >> 1, kk = p & 1;
      if (p == 0 && t + 1 < KT) stage_a256(A, m0, Kdim, t + 1, 1, Asm);
      if (p == 1 && t + 1 < KT) stage_b256(Bt, n0, Kdim, t + 1, 0, Bsm);
      if (p == 2 && t + 1 < KT) stage_b256(Bt, n0, Kdim, t + 1, 1, Bsm);
      if (p == 3 && t + 2 < KT) stage_a256(A, m0, Kdim, t + 2, 0, Asm);
      __builtin_amdgcn_sched_barrier(0);

      bfx8 af[4], bf[4];
      const int cbv = kk * 64 + g * 16;
#pragma unroll
      for (int j = 0; j < 4; ++j) {
        int arow = wm * 128 + (ah * 4 + j) * 16 + ql;
        af[j] = *(const bfx8*)(Ab + arow * 128 + (cbv ^ ((arow & 7) << 4)));
      }
#pragma unroll
      for (int nf = 0; nf < 4; ++nf) {
        int brow = wn * 64 + nf * 16 + ql;
        bf[nf] = *(const bfx8*)(Bb + brow * 128 + (cbv ^ ((brow & 7) << 4)));
      }
      __builtin_amdgcn_sched_barrier(0);
      __builtin_amdgcn_s_barrier();
      asm volatile("s_waitcnt lgkmcnt(0)" ::: "memory");
      __builtin_amdgcn_sched_barrier(0);
      __builtin_amdgcn_s_setprio(1);
#pragma unroll
      for (int j = 0; j < 4; ++j)
#pragma unroll
        for (int nf = 0; nf < 4; ++nf)
          acc[ah * 4 + j][nf] = __builtin_amdgcn_mfma_f32_16x16x32_bf16(
              af[j], bf[nf], acc[ah * 4 + j][nf], 0, 0, 0);
      __builtin_amdgcn_s_setprio(0);
      __builtin_amdgcn_s_barrier();
      __builtin_amdgcn_sched_barrier(0);
    }
    if (t + 1 < KT) {
      if (t + 2 < KT) asm volatile("s_waitcnt vmcnt(2)" ::: "memory");
      else            asm volatile("s_waitcnt vmcnt(0)" ::: "memory");
      __builtin_amdgcn_s_barrier();
      __builtin_amdgcn_sched_barrier(0);
    }
  }

#pragma unroll
  for (int mf = 0; mf < 8; ++mf) {
#pragma unroll
    for (int nf = 0; nf < 4; ++nf) {
      int col = n0 + wn * 64 + nf * 16 + ql;
      float bvl = bias[col];
#pragma unroll
      for (int r = 0; r < 4; ++r) {
        int rowg = m0 + wm * 128 + mf * 16 + g * 4 + r;
        float v = acc[mf][nf][r] + bvl;
        if (MODE == 2) v = 0.5f * v * (1.0f + fast_erf(v * 0.70710678118654752f));
        if (MODE == 1) ((float*)out)[(size_t)rowg * Ndim + col] = v;
        else          ((__bf16*)out)[(size_t)rowg * Ndim + col] = (__bf16)v;
      }
    }
  }
}

template<int MODE>
__global__ __launch_bounds__(512)
void gemm256_kernel(const __bf16* __restrict__ A, const __bf16* __restrict__ Bt,
                    const float* __restrict__ bias, void* __restrict__ out,
                    int Ndim, int Kdim) {
  const int gX  = gridDim.x;
  const int nwg = gridDim.x * gridDim.y;
  int lid = blockIdx.y * gX + blockIdx.x;
  int swz = (lid & 7) * (nwg >> 3) + (lid >> 3);
  gemm256_body<MODE>(A, Bt, bias, out, Ndim, Kdim,
                     (swz / gX) * 256, (swz % gX) * 256);
}

// --------------------------------------------------------- flash attention
// (round-25 validated: 48 KB LDS, XCD-chunked swizzle, unchanged)
__global__ __launch_bounds__(512)
void attn_kernel(const __bf16* __restrict__ Qb, const __bf16* __restrict__ Kb,
                 const __bf16* __restrict__ Vt, const float* __restrict__ mask2,
                 __bf16* __restrict__ ctx) {
  __shared__ alignas(16) __bf16 Ks[2 * 64 * 64];     // 16 KB (dbuf)
  __shared__ alignas(16) __bf16 Vs[2 * 64 * 64];     // 16 KB (dbuf)
  __shared__ alignas(16) __bf16 Ps[8 * 16 * 64];     // 16 KB (aliased by Q stage)

  const int tid  = threadIdx.x;
  const int lane = tid & 63;
  const int w    = tid >> 6;
  const int g    = lane >> 4;
  const int ql   = lane & 15;

  int hid = blockIdx.y * gridDim.x + blockIdx.x;
  int swz = (hid & 7) * 64 + (hid >> 3);
  const int bh   = swz >> 4;          // 0..31
  const int b    = bh >> 4;
  const int h    = bh & 15;
  const int q0   = (swz & 15) * 128;

  const size_t kbase  = ((size_t)(b * S_)) * D_ + h * DH_;
  const size_t vtbase = (size_t)bh * DH_ * S_;
  const int NT = S_ / 64;

  char* Qsm = (char*)Ps;                             // overlay
  const size_t qbase = ((size_t)(b * S_) + q0) * D_ + h * DH_;
#pragma unroll
  for (int i = 0; i < 2; ++i) {
    int o   = tid * 16 + i * 8192;
    int row = o >> 7, cb = o & 127;
    int cbs = cb ^ ((row & 7) << 4);
    gload_lds16((const char*)Qb + (qbase + (size_t)row * D_) * 2 + cbs, Qsm + o);
  }
  {
    int o   = tid * 16;
    int row = o >> 7, cb = o & 127;
    int cbs = cb ^ ((row & 7) << 4);
    gload_lds16((const char*)Kb + (kbase + (size_t)row * D_) * 2 + cbs, (char*)Ks + o);
    gload_lds16((const char*)Vt + (vtbase + (size_t)row * S_) * 2 + cbs, (char*)Vs + o);
  }
  asm volatile("s_waitcnt vmcnt(2)" ::: "memory");   // Q landed (tile0 in flight)
  __builtin_amdgcn_s_barrier();
  __builtin_amdgcn_sched_barrier(0);

  bfx8 aq[2];
  {
    int row = w * 16 + ql;
#pragma unroll
    for (int kk = 0; kk < 2; ++kk) {
      int cb = kk * 64 + g * 16;
      aq[kk] = *(const bfx8*)(Qsm + row * 128 + (cb ^ ((row & 7) << 4)));
    }
  }
  __syncthreads();                                   // aq reads done -> Ps free
  asm volatile("s_waitcnt vmcnt(0)" ::: "memory");   // tile0 landed
  __builtin_amdgcn_s_barrier();
  __builtin_amdgcn_sched_barrier(0);

  fx4 acc[4];
  fx4 accl = {0.f, 0.f, 0.f, 0.f};                   // row-sum accumulator
#pragma unroll
  for (int d = 0; d < 4; ++d) acc[d] = {0.f, 0.f, 0.f, 0.f};

  bfx8 ones;
#pragma unroll
  for (int j = 0; j < 8; ++j) ones[j] = (__bf16)1.0f;

  char* pw = (char*)Ps + w * 2048;
  const float SCL = 0.18033688f;                     // 0.125 * log2(e)
  const float* mrow = mask2 + (size_t)b * S_;

  for (int t = 0; t < NT; ++t) {
    const int kv0 = t * 64;
    float4 mk[4];
#pragma unroll
    for (int nf = 0; nf < 4; ++nf)
      mk[nf] = *(const float4*)(mrow + kv0 + nf * 16 + g * 4);
    __builtin_amdgcn_sched_barrier(0);
    if (t + 1 < NT) {                 // stage tile t+1 into buf (t+1)&1
      int o   = tid * 16;
      int row = o >> 7, cb = o & 127;
      int cbs = cb ^ ((row & 7) << 4);
      int nkv = kv0 + 64;
      int bo  = ((t + 1) & 1) * 8192;
      gload_lds16((const char*)Kb + (kbase + (size_t)(nkv + row) * D_) * 2 + cbs,
                  (char*)Ks + bo + o);
      gload_lds16((const char*)Vt + (vtbase + (size_t)row * S_ + nkv) * 2 + cbs,
                  (char*)Vs + bo + o);
    }
    __builtin_amdgcn_sched_barrier(0);
    const char* Kc = (const char*)Ks + (t & 1) * 8192;
    const char* Vc = (const char*)Vs + (t & 1) * 8192;

    // swapped QK^T
    fx4 sc[4];
#pragma unroll
    for (int nf = 0; nf < 4; ++nf) sc[nf] = {0.f, 0.f, 0.f, 0.f};
#pragma unroll
    for (int kk = 0; kk < 2; ++kk) {
      const int cb = kk * 64 + g * 16;
      bfx8 bk[4];
#pragma unroll
      for (int nf = 0; nf < 4; ++nf) {
        int row = nf * 16 + ql;
        bk[nf] = *(const bfx8*)(Kc + row * 128 + (cb ^ ((row & 7) << 4)));
      }
      __builtin_amdgcn_s_setprio(1);
#pragma unroll
      for (int nf = 0; nf < 4; ++nf)
        sc[nf] = __builtin_amdgcn_mfma_f32_16x16x32_bf16(bk[nf], aq[kk], sc[nf], 0, 0, 0);
      __builtin_amdgcn_s_setprio(0);
    }

    // static-max softmax: P = exp2(s*SCL + mask)  (bounded, no max needed)
    float sv[4][4];
#pragma unroll
    for (int nf = 0; nf < 4; ++nf) {
      sv[nf][0] = fast_exp2(fmaf(sc[nf][0], SCL, mk[nf].x));
      sv[nf][1] = fast_exp2(fmaf(sc[nf][1], SCL, mk[nf].y));
      sv[nf][2] = fast_exp2(fmaf(sc[nf][2], SCL, mk[nf].z));
      sv[nf][3] = fast_exp2(fmaf(sc[nf][3], SCL, mk[nf].w));
    }

    // write P strip row ql (vector bfx4)
#pragma unroll
    for (int nf = 0; nf < 4; ++nf) {
      bfx4 pv;
      pv[0] = (__bf16)sv[nf][0]; pv[1] = (__bf16)sv[nf][1];
      pv[2] = (__bf16)sv[nf][2]; pv[3] = (__bf16)sv[nf][3];
      int c = (nf * 32 + g * 8) ^ ((ql & 7) << 4);
      *(bfx4*)(pw + ql * 128 + c) = pv;
    }

    // fence: P-strip writes complete + no compiler motion of PV reads above
    asm volatile("s_waitcnt lgkmcnt(0)" ::: "memory");
    __builtin_amdgcn_sched_barrier(0);

    // PV + row-sum (ones-operand)
#pragma unroll
    for (int kk = 0; kk < 2; ++kk) {
      int prow = ql;
      int cb   = kk * 64 + g * 16;
      bfx8 ap  = *(const bfx8*)((const char*)pw + prow * 128 + (cb ^ ((prow & 7) << 4)));
      __builtin_amdgcn_s_setprio(1);
#pragma unroll
      for (int d = 0; d < 4; ++d) {
        int vrow = d * 16 + ql;
        bfx8 bv  = *(const bfx8*)(Vc + vrow * 128 + (cb ^ ((vrow & 7) << 4)));
        acc[d] = __builtin_amdgcn_mfma_f32_16x16x32_bf16(ap, bv, acc[d], 0, 0, 0);
      }
      accl = __builtin_amdgcn_mfma_f32_16x16x32_bf16(ap, ones, accl, 0, 0, 0);
      __builtin_amdgcn_s_setprio(0);
    }

    // end-of-iter: tile t+1 resident + buffer protection; ONE barrier
    if (t + 1 < NT) {
      asm volatile("s_waitcnt vmcnt(0)" ::: "memory");
      __builtin_amdgcn_s_barrier();
      __builtin_amdgcn_sched_barrier(0);
    }
  }

  // finalize: denominator lane-local in accl[r]
#pragma unroll
  for (int r = 0; r < 4; ++r) {
    float inv = 1.0f / accl[r];
    int qrow = q0 + w * 16 + g * 4 + r;
    size_t base = ((size_t)(b * S_) + qrow) * D_ + h * DH_;
#pragma unroll
    for (int d = 0; d < 4; ++d)
      ctx[base + d * 16 + ql] = (__bf16)(acc[d][r] * inv);
  }
}

// -------------------- LayerNorm over presummed bf16 input (row=1024)
template<bool WRITE_BF16>
__global__ __launch_bounds__(256)
void ln_kernel(const __bf16* __restrict__ a,
               const float* __restrict__ g, const float* __restrict__ beta,
               float* __restrict__ outf, __bf16* __restrict__ outb) {
  const int row = blockIdx.x;
  const int tid = threadIdx.x;
  const size_t base = (size_t)row * D_;
  bfx4 xa = *(const bfx4*)(a + base + tid * 4);
  float x[4] = {(float)xa[0], (float)xa[1], (float)xa[2], (float)xa[3]};
  float s = x[0] + x[1] + x[2] + x[3];
#pragma unroll
  for (int m = 1; m < 64; m <<= 1) s += __shfl_xor(s, m);
  __shared__ float red[8];
  if ((tid & 63) == 0) red[tid >> 6] = s;
  __syncthreads();
  float mu = (red[0] + red[1] + red[2] + red[3]) * (1.0f / D_);
  float v0 = 0.f;
#pragma unroll
  for (int i = 0; i < 4; ++i) { float d = x[i] - mu; v0 += d * d; }
#pragma unroll
  for (int m = 1; m < 64; m <<= 1) v0 += __shfl_xor(v0, m);
  if ((tid & 63) == 0) red[4 + (tid >> 6)] = v0;
  __syncthreads();
  float var = (red[4] + red[5] + red[6] + red[7]) * (1.0f / D_);
  float rs = rsqrtf(var + 1e-12f);
#pragma unroll
  for (int i = 0; i < 4; ++i) {
    int col = tid * 4 + i;
    x[i] = (x[i] - mu) * rs * g[col] + beta[col];
  }
  if (WRITE_BF16) {
    bfx4 o;
    o[0] = (__bf16)x[0]; o[1] = (__bf16)x[1]; o[2] = (__bf16)x[2]; o[3] = (__bf16)x[3];
    *(bfx4*)(outb + base + tid * 4) = o;
  } else {
    *(float4*)(outf + base + tid * 4) = make_float4(x[0], x[1], x[2], x[3]);
  }
}

// ---------------------------------------------------------------- launch
extern "C" void kernel_launch(void* const* d_in, const int* in_sizes, int n_in,
                              void* d_out, int out_size, void* d_ws, size_t ws_size,
                              hipStream_t stream) {
  const float* query    = (const float*)d_in[0];
  const float* key_in   = (const float*)d_in[1];
  const float* value_in = (const float*)d_in[2];
  const float* mask     = (const float*)d_in[3];
  const float* Wq = (const float*)d_in[4];  const float* bq = (const float*)d_in[5];
  const float* Wk = (const float*)d_in[6];  const float* bk = (const float*)d_in[7];
  const float* Wv = (const float*)d_in[8];  const float* bv = (const float*)d_in[9];
  const float* Wo = (const float*)d_in[10]; const float* bo = (const float*)d_in[11];
  const float* ln1g = (const float*)d_in[12]; const float* ln1b = (const float*)d_in[13];
  const float* Wi = (const float*)d_in[14]; const float* bi = (const float*)d_in[15];
  const float* Wd = (const float*)d_in[16]; const float* bd = (const float*)d_in[17];
  const float* ln2g = (const float*)d_in[18]; const float* ln2b = (const float*)d_in[19];

  char* ws = (char*)d_ws;
  const size_t MB = 1ull << 20;
  if (ws_size < 112 * MB) return;

  __bf16* xq   = (__bf16*)(ws + 0 * MB);
  __bf16* xk   = (__bf16*)(ws + 8 * MB);
  __bf16* xv   = (__bf16*)(ws + 16 * MB);
  __bf16* x1b  = (__bf16*)(ws + 16 * MB);
  __bf16* qb   = (__bf16*)(ws + 24 * MB);
  __bf16* inter= (__bf16*)(ws + 24 * MB);
  __bf16* kb   = (__bf16*)(ws + 32 * MB);
  __bf16* alinb= (__bf16*)(ws + 40 * MB);
  __bf16* vt   = (__bf16*)(ws + 48 * MB);
  __bf16* ctxb = (__bf16*)(ws + 56 * MB);
  __bf16* ffb  = (__bf16*)(ws + 56 * MB);
  float*  mask2= (float*)(ws + 72 * MB);    // pre-scaled mask (16 KB)
  __bf16* wqt  = (__bf16*)(ws + 88 * MB);
  __bf16* wkt  = (__bf16*)(ws + 90 * MB);
  __bf16* wvt  = (__bf16*)(ws + 92 * MB);
  __bf16* wot  = (__bf16*)(ws + 94 * MB);
  __bf16* wit  = (__bf16*)(ws + 96 * MB);
  __bf16* wdt  = (__bf16*)(ws + 104 * MB);

  dim3 b256(256);

  PrepArgs pa;
  pa.win[0] = Wq; pa.win[1] = Wk; pa.win[2] = Wv; pa.win[3] = Wo;
  pa.win[4] = Wi; pa.win[5] = Wd;
  pa.wout[0] = wqt; pa.wout[1] = wkt; pa.wout[2] = wvt; pa.wout[3] = wot;
  pa.wout[4] = wit; pa.wout[5] = wdt;
  pa.cin[0] = query; pa.cin[1] = key_in; pa.cin[2] = value_in;
  pa.cout[0] = xq;   pa.cout[1] = xk;    pa.cout[2] = xv;
  pa.min = mask; pa.mout = mask2;
  prep_kernel<<<dim3(24580), b256, 0, stream>>>(pa);

  QKVArgs qa;
  qa.A[0] = xq;  qa.A[1] = xk;  qa.A[2] = xv;
  qa.Bt[0] = wqt; qa.Bt[1] = wkt; qa.Bt[2] = wvt;
  qa.bias[0] = bq; qa.bias[1] = bk; qa.bias[2] = bv;
  qa.out[0] = qb; qa.out[1] = kb; qa.out[2] = vt;   // V -> transposed direct
  qkv128_kernel<<<dim3(D_ / 128, M_ / 128, 3), b256, 0, stream>>>(qa, D_, D_);

  attn_kernel<<<dim3(S_ / 128, B_ * H_), dim3(512), 0, stream>>>(qb, kb, vt, mask2, ctxb);

  // Wo: 64x64 tiles, 1024 blocks (4/CU)
  gemm_kernel<4, 64, 64><<<dim3(D_ / 64, M_ / 64), b256, 0, stream>>>(ctxb, wot, bo, xq, (void*)alinb, D_, D_);

  ln_kernel<true><<<dim3(M_), b256, 0, stream>>>(alinb, ln1g, ln1b, nullptr, x1b);

  gemm256_kernel<2><<<dim3(DFF_ / 256, M_ / 256), dim3(512), 131072, stream>>>(x1b, wit, bi, (void*)inter, DFF_, D_);

  // Wd: 64x64 tiles, 1024 blocks (4/CU)
  gemm_kernel<4, 64, 64><<<dim3(D_ / 64, M_ / 64), b256, 0, stream>>>(inter, wdt, bd, x1b, (void*)ffb, D_, DFF_);

  ln_kernel<false><<<dim3(M_), b256, 0, stream>>>(ffb, ln2g, ln2b, (float*)d_out, nullptr);
}

// Round 27
// 229.832 us; speedup vs baseline: 1.0061x; 1.0061x over previous
//
#include <hip/hip_runtime.h>
#include <hip/hip_bf16.h>
#include <cmath>

#define B_   2
#define S_   2048
#define D_   1024
#define H_   16
#define DFF_ 4096
#define DH_  64
#define M_   (B_*S_)   // 4096 rows

typedef __bf16 bfx8 __attribute__((ext_vector_type(8)));
typedef __bf16 bfx4 __attribute__((ext_vector_type(4)));
typedef float  fx4  __attribute__((ext_vector_type(4)));

__device__ __forceinline__ float fast_exp2(float x) {
  float r;
  asm volatile("v_exp_f32 %0, %1" : "=v"(r) : "v"(x));
  return r;
}

// Abramowitz-Stegun 7.1.26 erf (max abs err 1.5e-7; exact at bf16 granularity)
__device__ __forceinline__ float fast_erf(float x) {
  float ax = fabsf(x);
  float t  = __builtin_amdgcn_rcpf(fmaf(0.3275911f, ax, 1.0f));
  float p  = fmaf(1.061405429f, t, -1.453152027f);
  p = fmaf(p, t, 1.421413741f);
  p = fmaf(p, t, -0.284496736f);
  p = fmaf(p, t, 0.254829592f);
  p = p * t;
  float e  = fast_exp2(-ax * ax * 1.44269504f);
  float r  = 1.0f - p * e;
  return copysignf(r, x);
}

// ---------------------------------------------------------------- utilities
__device__ __forceinline__ void gload_lds16(const void* g, void* l) {
  __builtin_amdgcn_global_load_lds((__attribute__((address_space(1))) void*)(g),
                                   (__attribute__((address_space(3))) void*)(l),
                                   16, 0, 0);
}

// --- combined preprocessing: 6 weight transposes + 3 fp32->bf16 + mask scale
struct PrepArgs {
  const float* win[6]; __bf16* wout[6];
  const float* cin[3]; __bf16* cout[3];
  const float* min;    float* mout;     // mask * log2(e) -> global f32
};

__global__ __launch_bounds__(256)
void prep_kernel(PrepArgs a) {
  int bid = blockIdx.x;
  if (bid < 12288) {
    __shared__ float t[32][33];
    int wsel, tr, tc, R, C;
    if (bid < 4096) {
      wsel = bid >> 10; int l = bid & 1023;
      tr = l >> 5; tc = l & 31; R = D_; C = D_;
    } else if (bid < 8192) {
      wsel = 4; int l = bid - 4096;
      tr = l >> 7; tc = l & 127; R = D_; C = DFF_;
    } else {
      wsel = 5; int l = bid - 8192;
      tr = l >> 5; tc = l & 31; R = DFF_; C = D_;
    }
    const float* in = a.win[wsel];
    __bf16* out = a.wout[wsel];
    int r0 = tr * 32, c0 = tc * 32;
    int tx = threadIdx.x & 31, ty = threadIdx.x >> 5;   // 32 x 8
#pragma unroll
    for (int j = 0; j < 4; ++j) {
      int r = ty + j * 8;
      t[r][tx] = in[(size_t)(r0 + r) * C + c0 + tx];
    }
    __syncthreads();
#pragma unroll
    for (int j = 0; j < 4; ++j) {
      int c = ty + j * 8;
      out[(size_t)(c0 + c) * R + r0 + tx] = (__bf16)t[tx][c];
    }
  } else if (bid < 24576) {
    int l = bid - 12288;
    int z = l >> 12;                      // 0..2
    int i = ((l & 4095) * 256 + threadIdx.x) * 4;
    float4 v = *(const float4*)(a.cin[z] + i);
    bfx4 o;
    o[0] = (__bf16)v.x; o[1] = (__bf16)v.y; o[2] = (__bf16)v.z; o[3] = (__bf16)v.w;
    *(bfx4*)(a.cout[z] + i) = o;
  } else {
    int i = ((bid - 24576) * 256 + threadIdx.x) * 4;  // 4 blocks x 1024 = 4096
    float4 v = *(const float4*)(a.min + i);
    v.x *= 1.44269504f; v.y *= 1.44269504f;
    v.z *= 1.44269504f; v.w *= 1.44269504f;
    *(float4*)(a.mout + i) = v;
  }
}

// --------------------------------------------------------------- GEMM tile
// Double-buffered, counted-vmcnt + XCD-chunked swizzle; BM templated
// (round-24 validated: Wo/Wd at 64x64, 4 blocks/CU).
template<int MODE, int BM, int TBN>
__global__ __launch_bounds__(256)
void gemm_kernel(const __bf16* __restrict__ A, const __bf16* __restrict__ Bt,
                 const float* __restrict__ bias, const void* __restrict__ res,
                 void* __restrict__ out, int Ndim, int Kdim) {
  __shared__ alignas(16) __bf16 As[2 * BM * 64];
  __shared__ alignas(16) __bf16 Bs[2 * TBN * 64];
  const int tid  = threadIdx.x;
  const int lane = tid & 63;
  const int w    = tid >> 6;
  const int wm   = w >> 1, wn = w & 1;
  constexpr int MF = BM / 32;
  constexpr int NF = TBN / 32;
  constexpr int AL = BM / 32;
  constexpr int BL = TBN / 32;
  constexpr int VM = AL + BL;

  const int gX  = gridDim.x;
  const int nwg = gridDim.x * gridDim.y;
  int lid = blockIdx.y * gX + blockIdx.x;
  int swz = (lid & 7) * (nwg >> 3) + (lid >> 3);
  const int m0 = (swz / gX) * BM, n0 = (swz % gX) * TBN;

  fx4 acc[MF][NF];
#pragma unroll
  for (int i = 0; i < MF; ++i)
#pragma unroll
    for (int j = 0; j < NF; ++j) acc[i][j] = {0.f, 0.f, 0.f, 0.f};

  const int KT = Kdim / 64;

  auto stage = [&](int kt, int buf) {
    const int kb0 = kt * 64;
#pragma unroll
    for (int i = 0; i < AL; ++i) {
      int o   = tid * 16 + i * 4096;
      int row = o >> 7, cb = o & 127;
      int cbs = cb ^ ((row & 7) << 4);
      gload_lds16((const char*)A + ((size_t)(m0 + row) * Kdim + kb0) * 2 + cbs,
                  (char*)As + buf * (BM * 128) + o);
    }
#pragma unroll
    for (int i = 0; i < BL; ++i) {
      int o   = tid * 16 + i * 4096;
      int row = o >> 7, cb = o & 127;
      int cbs = cb ^ ((row & 7) << 4);
      gload_lds16((const char*)Bt + ((size_t)(n0 + row) * Kdim + kb0) * 2 + cbs,
                  (char*)Bs + buf * (TBN * 128) + o);
    }
  };

  stage(0, 0);
  asm volatile("s_waitcnt vmcnt(0)" ::: "memory");
  __builtin_amdgcn_s_barrier();
  __builtin_amdgcn_sched_barrier(0);

  for (int kt = 0; kt < KT; ++kt) {
    if (kt + 1 < KT) stage(kt + 1, (kt + 1) & 1);
    __builtin_amdgcn_sched_barrier(0);
    if (kt > 0) {
      if (kt + 1 < KT) {
        if constexpr (VM == 4)      asm volatile("s_waitcnt vmcnt(4)" ::: "memory");
        else if constexpr (VM == 6) asm volatile("s_waitcnt vmcnt(6)" ::: "memory");
        else                        asm volatile("s_waitcnt vmcnt(8)" ::: "memory");
      } else {
        asm volatile("s_waitcnt vmcnt(0)" ::: "memory");
      }
      __builtin_amdgcn_s_barrier();
      __builtin_amdgcn_sched_barrier(0);
    }
    const char* Ab = (const char*)As + (kt & 1) * (BM * 128);
    const char* Bb = (const char*)Bs + (kt & 1) * (TBN * 128);

#pragma unroll
    for (int kk = 0; kk < 2; ++kk) {
      bfx8 afr[MF], bfr[NF];
      const int cb = kk * 64 + ((lane >> 4) << 4);
#pragma unroll
      for (int mf = 0; mf < MF; ++mf) {
        int row = wm * (BM / 2) + mf * 16 + (lane & 15);
        afr[mf] = *(const bfx8*)(Ab + row * 128 + (cb ^ ((row & 7) << 4)));
      }
#pragma unroll
      for (int nf = 0; nf < NF; ++nf) {
        int row = wn * (TBN / 2) + nf * 16 + (lane & 15);
        bfr[nf] = *(const bfx8*)(Bb + row * 128 + (cb ^ ((row & 7) << 4)));
      }
#pragma unroll
      for (int mf = 0; mf < MF; ++mf)
#pragma unroll
        for (int nf = 0; nf < NF; ++nf)
          acc[mf][nf] = __builtin_amdgcn_mfma_f32_16x16x32_bf16(afr[mf], bfr[nf],
                                                                acc[mf][nf], 0, 0, 0);
    }
    __builtin_amdgcn_s_barrier();
    __builtin_amdgcn_sched_barrier(0);
  }

#pragma unroll
  for (int mf = 0; mf < MF; ++mf) {
#pragma unroll
    for (int nf = 0; nf < NF; ++nf) {
      int col = n0 + wn * (TBN / 2) + nf * 16 + (lane & 15);
      float bvl = bias[col];
#pragma unroll
      for (int r = 0; r < 4; ++r) {
        int rowg = m0 + wm * (BM / 2) + mf * 16 + ((lane >> 4) << 2) + r;
        float v = acc[mf][nf][r] + bvl;
        if (MODE == 2) v = 0.5f * v * (1.0f + fast_erf(v * 0.70710678118654752f));
        if (MODE == 4) v += (float)((const __bf16*)res)[(size_t)rowg * Ndim + col];
        if (MODE == 1) ((float*)out)[(size_t)rowg * Ndim + col] = v;
        else           ((__bf16*)out)[(size_t)rowg * Ndim + col] = (__bf16)v;
      }
    }
  }
}

// --------------------------------------------------------------- GEMM 256-tile
// MODE 0: bf16 row-major. MODE 2: GELU bf16. MODE 5: transposed V store.
__device__ __forceinline__ void stage_a256(const __bf16* __restrict__ A, int m0,
                                           int Kdim, int tile, int h, char* Asm) {
  char* dst = Asm + (tile & 1) * 32768;
  const int kb0 = tile * 64;
  const int tid = threadIdx.x;
#pragma unroll
  for (int it = 0; it < 2; ++it) {
    int o = tid * 16 + it * 8192;
    int lrow = o >> 7, cb = o & 127;
    int r = (lrow & 63) + h * 64 + ((lrow >> 6) << 7);
    int csrc = cb ^ ((r & 7) << 4);
    gload_lds16((const char*)A + ((size_t)(m0 + r) * Kdim + kb0) * 2 + csrc,
                dst + r * 128 + cb);
  }
}
__device__ __forceinline__ void stage_b256(const __bf16* __restrict__ Bt, int n0,
                                           int Kdim, int tile, int h, char* Bsm) {
  char* dst = Bsm + (tile & 1) * 32768;
  const int kb0 = tile * 64;
  const int tid = threadIdx.x;
#pragma unroll
  for (int it = 0; it < 2; ++it) {
    int o = tid * 16 + it * 8192;
    int lrow = o >> 7, cb = o & 127;
    int r = h * 128 + lrow;
    int csrc = cb ^ ((r & 7) << 4);
    gload_lds16((const char*)Bt + ((size_t)(n0 + r) * Kdim + kb0) * 2 + csrc,
                dst + r * 128 + cb);
  }
}

template<int MODE>
__device__ __forceinline__ void gemm256_body(const __bf16* __restrict__ A,
                                             const __bf16* __restrict__ Bt,
                                             const float* __restrict__ bias,
                                             void* __restrict__ out,
                                             int Ndim, int Kdim, int m0, int n0) {
  extern __shared__ char smem[];
  char* Asm = smem;
  char* Bsm = smem + 65536;
  const int tid  = threadIdx.x;
  const int lane = tid & 63;
  const int w    = tid >> 6;
  const int wm   = w >> 2;
  const int wn   = w & 3;
  const int g    = lane >> 4;
  const int ql   = lane & 15;
  const int KT   = Kdim / 64;

  fx4 acc[8][4];
#pragma unroll
  for (int i = 0; i < 8; ++i)
#pragma unroll
    for (int j = 0; j < 4; ++j) acc[i][j] = {0.f, 0.f, 0.f, 0.f};

  stage_a256(A, m0, Kdim, 0, 0, Asm);
  stage_a256(A, m0, Kdim, 0, 1, Asm);
  stage_b256(Bt, n0, Kdim, 0, 0, Bsm);
  stage_b256(Bt, n0, Kdim, 0, 1, Bsm);
  stage_a256(A, m0, Kdim, 1, 0, Asm);
  asm volatile("s_waitcnt vmcnt(2)" ::: "memory");
  __builtin_amdgcn_s_barrier();
  __builtin_amdgcn_sched_barrier(0);

  for (int t = 0; t < KT; ++t) {
    const char* Ab = Asm + (t & 1) * 32768;
    const char* Bb = Bsm + (t & 1) * 32768;
#pragma unroll
    for (int p = 0; p < 4; ++p) {
      const int ah = p >> 1, kk = p & 1;
      if (p == 0 && t + 1 < KT) stage_a256(A, m0, Kdim, t + 1, 1, Asm);
      if (p == 1 && t + 1 < KT) stage_b256(Bt, n0, Kdim, t + 1, 0, Bsm);
      if (p == 2 && t + 1 < KT) stage_b256(Bt, n0, Kdim, t + 1, 1, Bsm);
      if (p == 3 && t + 2 < KT) stage_a256(A, m0, Kdim, t + 2, 0, Asm);
      __builtin_amdgcn_sched_barrier(0);

      bfx8 af[4], bf[4];
      const int cbv = kk * 64 + g * 16;
#pragma unroll
      for (int j = 0; j < 4; ++j) {
        int arow = wm * 128 + (ah * 4 + j) * 16 + ql;
        af[j] = *(const bfx8*)(Ab + arow * 128 + (cbv ^ ((arow & 7) << 4)));
      }
#pragma unroll
      for (int nf = 0; nf < 4; ++nf) {
        int brow = wn * 64 + nf * 16 + ql;
        bf[nf] = *(const bfx8*)(Bb + brow * 128 + (cbv ^ ((brow & 7) << 4)));
      }
      __builtin_amdgcn_sched_barrier(0);
      __builtin_amdgcn_s_barrier();
      asm volatile("s_waitcnt lgkmcnt(0)" ::: "memory");
      __builtin_amdgcn_sched_barrier(0);
      __builtin_amdgcn_s_setprio(1);
#pragma unroll
      for (int j = 0; j < 4; ++j)
#pragma unroll
        for (int nf = 0; nf < 4; ++nf)
          acc[ah * 4 + j][nf] = __builtin_amdgcn_mfma_f32_16x16x32_bf16(
              af[j], bf[nf], acc[ah * 4 + j][nf], 0, 0, 0);
      __builtin_amdgcn_s_setprio(0);
      __builtin_amdgcn_s_barrier();
      __builtin_amdgcn_sched_barrier(0);
    }
    if (t + 1 < KT) {
      if (t + 2 < KT) asm volatile("s_waitcnt vmcnt(2)" ::: "memory");
      else            asm volatile("s_waitcnt vmcnt(0)" ::: "memory");
      __builtin_amdgcn_s_barrier();
      __builtin_amdgcn_sched_barrier(0);
    }
  }

#pragma unroll
  for (int mf = 0; mf < 8; ++mf) {
#pragma unroll
    for (int nf = 0; nf < 4; ++nf) {
      int col = n0 + wn * 64 + nf * 16 + ql;
      float bvl = bias[col];
      if (MODE == 5) {
        int rowg0 = m0 + wm * 128 + mf * 16 + g * 4;   // 4 consecutive s
        int bb = rowg0 >> 11, s = rowg0 & 2047;        // S_=2048
        int hh = col >> 6, dh = col & 63;
        bfx4 o;
#pragma unroll
        for (int r = 0; r < 4; ++r) o[r] = (__bf16)(acc[mf][nf][r] + bvl);
        *(bfx4*)((__bf16*)out + (((size_t)(bb * 16 + hh) * 64 + dh) * 2048 + s)) = o;
      } else {
#pragma unroll
        for (int r = 0; r < 4; ++r) {
          int rowg = m0 + wm * 128 + mf * 16 + g * 4 + r;
          float v = acc[mf][nf][r] + bvl;
          if (MODE == 2) v = 0.5f * v * (1.0f + fast_erf(v * 0.70710678118654752f));
          if (MODE == 1) ((float*)out)[(size_t)rowg * Ndim + col] = v;
          else          ((__bf16*)out)[(size_t)rowg * Ndim + col] = (__bf16)v;
        }
      }
    }
  }
}

template<int MODE>
__global__ __launch_bounds__(512)
void gemm256_kernel(const __bf16* __restrict__ A, const __bf16* __restrict__ Bt,
                    const float* __restrict__ bias, void* __restrict__ out,
                    int Ndim, int Kdim) {
  const int gX  = gridDim.x;
  const int nwg = gridDim.x * gridDim.y;
  int lid = blockIdx.y * gX + blockIdx.x;
  int swz = (lid & 7) * (nwg >> 3) + (lid >> 3);
  gemm256_body<MODE>(A, Bt, bias, out, Ndim, Kdim,
                     (swz / gX) * 256, (swz % gX) * 256);
}

struct QKVArgs {
  const __bf16* A[3]; const __bf16* Bt[3]; const float* bias[3]; __bf16* out[3];
};

__global__ __launch_bounds__(512)
void qkv256_kernel(QKVArgs args, int Ndim, int Kdim) {
  int z = blockIdx.z;
  const int gX  = gridDim.x;                         // 4
  const int nwg = gridDim.x * gridDim.y;             // 64
  int lid = blockIdx.y * gX + blockIdx.x;
  int swz = (lid & 7) * (nwg >> 3) + (lid >> 3);
  int m0 = (swz / gX) * 256, n0 = (swz % gX) * 256;
  if (z == 2)
    gemm256_body<5>(args.A[2], args.Bt[2], args.bias[2], (void*)args.out[2],
                    Ndim, Kdim, m0, n0);
  else
    gemm256_body<0>(args.A[z], args.Bt[z], args.bias[z], (void*)args.out[z],
                    Ndim, Kdim, m0, n0);
}

// --------------------------------------------------------- flash attention
// (round-25 validated: 48 KB LDS, XCD-chunked swizzle, static-max softmax,
// MFMA row-sum, depth-1 dbuf with clean vmcnt counts)
__global__ __launch_bounds__(512)
void attn_kernel(const __bf16* __restrict__ Qb, const __bf16* __restrict__ Kb,
                 const __bf16* __restrict__ Vt, const float* __restrict__ mask2,
                 __bf16* __restrict__ ctx) {
  __shared__ alignas(16) __bf16 Ks[2 * 64 * 64];     // 16 KB (dbuf)
  __shared__ alignas(16) __bf16 Vs[2 * 64 * 64];     // 16 KB (dbuf)
  __shared__ alignas(16) __bf16 Ps[8 * 16 * 64];     // 16 KB (aliased by Q stage)

  const int tid  = threadIdx.x;
  const int lane = tid & 63;
  const int w    = tid >> 6;
  const int g    = lane >> 4;
  const int ql   = lane & 15;

  int hid = blockIdx.y * gridDim.x + blockIdx.x;
  int swz = (hid & 7) * 64 + (hid >> 3);
  const int bh   = swz >> 4;          // 0..31
  const int b    = bh >> 4;
  const int h    = bh & 15;
  const int q0   = (swz & 15) * 128;

  const size_t kbase  = ((size_t)(b * S_)) * D_ + h * DH_;
  const size_t vtbase = (size_t)bh * DH_ * S_;
  const int NT = S_ / 64;

  char* Qsm = (char*)Ps;                             // overlay
  const size_t qbase = ((size_t)(b * S_) + q0) * D_ + h * DH_;
#pragma unroll
  for (int i = 0; i < 2; ++i) {
    int o   = tid * 16 + i * 8192;
    int row = o >> 7, cb = o & 127;
    int cbs = cb ^ ((row & 7) << 4);
    gload_lds16((const char*)Qb + (qbase + (size_t)row * D_) * 2 + cbs, Qsm + o);
  }
  {
    int o   = tid * 16;
    int row = o >> 7, cb = o & 127;
    int cbs = cb ^ ((row & 7) << 4);
    gload_lds16((const char*)Kb + (kbase + (size_t)row * D_) * 2 + cbs, (char*)Ks + o);
    gload_lds16((const char*)Vt + (vtbase + (size_t)row * S_) * 2 + cbs, (char*)Vs + o);
  }
  asm volatile("s_waitcnt vmcnt(2)" ::: "memory");   // Q landed (tile0 in flight)
  __builtin_amdgcn_s_barrier();
  __builtin_amdgcn_sched_barrier(0);

  bfx8 aq[2];
  {
    int row = w * 16 + ql;
#pragma unroll
    for (int kk = 0; kk < 2; ++kk) {
      int cb = kk * 64 + g * 16;
      aq[kk] = *(const bfx8*)(Qsm + row * 128 + (cb ^ ((row & 7) << 4)));
    }
  }
  __syncthreads();                                   // aq reads done -> Ps free
  asm volatile("s_waitcnt vmcnt(0)" ::: "memory");   // tile0 landed
  __builtin_amdgcn_s_barrier();
  __builtin_amdgcn_sched_barrier(0);

  fx4 acc[4];
  fx4 accl = {0.f, 0.f, 0.f, 0.f};                   // row-sum accumulator
#pragma unroll
  for (int d = 0; d < 4; ++d) acc[d] = {0.f, 0.f, 0.f, 0.f};

  bfx8 ones;
#pragma unroll
  for (int j = 0; j < 8; ++j) ones[j] = (__bf16)1.0f;

  char* pw = (char*)Ps + w * 2048;
  const float SCL = 0.18033688f;                     // 0.125 * log2(e)
  const float* mrow = mask2 + (size_t)b * S_;

  for (int t = 0; t < NT; ++t) {
    const int kv0 = t * 64;
    float4 mk[4];
#pragma unroll
    for (int nf = 0; nf < 4; ++nf)
      mk[nf] = *(const float4*)(mrow + kv0 + nf * 16 + g * 4);
    __builtin_amdgcn_sched_barrier(0);
    if (t + 1 < NT) {                 // stage tile t+1 into buf (t+1)&1
      int o   = tid * 16;
      int row = o >> 7, cb = o & 127;
      int cbs = cb ^ ((row & 7) << 4);
      int nkv = kv0 + 64;
      int bo  = ((t + 1) & 1) * 8192;
      gload_lds16((const char*)Kb + (kbase + (size_t)(nkv + row) * D_) * 2 + cbs,
                  (char*)Ks + bo + o);
      gload_lds16((const char*)Vt + (vtbase + (size_t)row * S_ + nkv) * 2 + cbs,
                  (char*)Vs + bo + o);
    }
    __builtin_amdgcn_sched_barrier(0);
    const char* Kc = (const char*)Ks + (t & 1) * 8192;
    const char* Vc = (const char*)Vs + (t & 1) * 8192;

    // swapped QK^T
    fx4 sc[4];
#pragma unroll
    for (int nf = 0; nf < 4; ++nf) sc[nf] = {0.f, 0.f, 0.f, 0.f};
#pragma unroll
    for (int kk = 0; kk < 2; ++kk) {
      const int cb = kk * 64 + g * 16;
      bfx8 bk[4];
#pragma unroll
      for (int nf = 0; nf < 4; ++nf) {
        int row = nf * 16 + ql;
        bk[nf] = *(const bfx8*)(Kc + row * 128 + (cb ^ ((row & 7) << 4)));
      }
      __builtin_amdgcn_s_setprio(1);
#pragma unroll
      for (int nf = 0; nf < 4; ++nf)
        sc[nf] = __builtin_amdgcn_mfma_f32_16x16x32_bf16(bk[nf], aq[kk], sc[nf], 0, 0, 0);
      __builtin_amdgcn_s_setprio(0);
    }

    // static-max softmax: P = exp2(s*SCL + mask)  (bounded, no max needed)
    float sv[4][4];
#pragma unroll
    for (int nf = 0; nf < 4; ++nf) {
      sv[nf][0] = fast_exp2(fmaf(sc[nf][0], SCL, mk[nf].x));
      sv[nf][1] = fast_exp2(fmaf(sc[nf][1], SCL, mk[nf].y));
      sv[nf][2] = fast_exp2(fmaf(sc[nf][2], SCL, mk[nf].z));
      sv[nf][3] = fast_exp2(fmaf(sc[nf][3], SCL, mk[nf].w));
    }

    // write P strip row ql (vector bfx4)
#pragma unroll
    for (int nf = 0; nf < 4; ++nf) {
      bfx4 pv;
      pv[0] = (__bf16)sv[nf][0]; pv[1] = (__bf16)sv[nf][1];
      pv[2] = (__bf16)sv[nf][2]; pv[3] = (__bf16)sv[nf][3];
      int c = (nf * 32 + g * 8) ^ ((ql & 7) << 4);
      *(bfx4*)(pw + ql * 128 + c) = pv;
    }

    // fence: P-strip writes complete + no compiler motion of PV reads above
    asm volatile("s_waitcnt lgkmcnt(0)" ::: "memory");
    __builtin_amdgcn_sched_barrier(0);

    // PV + row-sum (ones-operand)
#pragma unroll
    for (int kk = 0; kk < 2; ++kk) {
      int prow = ql;
      int cb   = kk * 64 + g * 16;
      bfx8 ap  = *(const bfx8*)((const char*)pw + prow * 128 + (cb ^ ((prow & 7) << 4)));
      __builtin_amdgcn_s_setprio(1);
#pragma unroll
      for (int d = 0; d < 4; ++d) {
        int vrow = d * 16 + ql;
        bfx8 bv  = *(const bfx8*)(Vc + vrow * 128 + (cb ^ ((vrow & 7) << 4)));
        acc[d] = __builtin_amdgcn_mfma_f32_16x16x32_bf16(ap, bv, acc[d], 0, 0, 0);
      }
      accl = __builtin_amdgcn_mfma_f32_16x16x32_bf16(ap, ones, accl, 0, 0, 0);
      __builtin_amdgcn_s_setprio(0);
    }

    // end-of-iter: tile t+1 resident + buffer protection; ONE barrier
    if (t + 1 < NT) {
      asm volatile("s_waitcnt vmcnt(0)" ::: "memory");
      __builtin_amdgcn_s_barrier();
      __builtin_amdgcn_sched_barrier(0);
    }
  }

  // finalize: denominator lane-local in accl[r]
#pragma unroll
  for (int r = 0; r < 4; ++r) {
    float inv = 1.0f / accl[r];
    int qrow = q0 + w * 16 + g * 4 + r;
    size_t base = ((size_t)(b * S_) + qrow) * D_ + h * DH_;
#pragma unroll
    for (int d = 0; d < 4; ++d)
      ctx[base + d * 16 + ql] = (__bf16)(acc[d][r] * inv);
  }
}

// -------------------- LayerNorm over presummed bf16 input (row=1024)
template<bool WRITE_BF16>
__global__ __launch_bounds__(256)
void ln_kernel(const __bf16* __restrict__ a,
               const float* __restrict__ g, const float* __restrict__ beta,
               float* __restrict__ outf, __bf16* __restrict__ outb) {
  const int row = blockIdx.x;
  const int tid = threadIdx.x;
  const size_t base = (size_t)row * D_;
  bfx4 xa = *(const bfx4*)(a + base + tid * 4);
  float x[4] = {(float)xa[0], (float)xa[1], (float)xa[2], (float)xa[3]};
  float s = x[0] + x[1] + x[2] + x[3];
#pragma unroll
  for (int m = 1; m < 64; m <<= 1) s += __shfl_xor(s, m);
  __shared__ float red[8];
  if ((tid & 63) == 0) red[tid >> 6] = s;
  __syncthreads();
  float mu = (red[0] + red[1] + red[2] + red[3]) * (1.0f / D_);
  float v0 = 0.f;
#pragma unroll
  for (int i = 0; i < 4; ++i) { float d = x[i] - mu; v0 += d * d; }
#pragma unroll
  for (int m = 1; m < 64; m <<= 1) v0 += __shfl_xor(v0, m);
  if ((tid & 63) == 0) red[4 + (tid >> 6)] = v0;
  __syncthreads();
  float var = (red[4] + red[5] + red[6] + red[7]) * (1.0f / D_);
  float rs = rsqrtf(var + 1e-12f);
#pragma unroll
  for (int i = 0; i < 4; ++i) {
    int col = tid * 4 + i;
    x[i] = (x[i] - mu) * rs * g[col] + beta[col];
  }
  if (WRITE_BF16) {
    bfx4 o;
    o[0] = (__bf16)x[0]; o[1] = (__bf16)x[1]; o[2] = (__bf16)x[2]; o[3] = (__bf16)x[3];
    *(bfx4*)(outb + base + tid * 4) = o;
  } else {
    *(float4*)(outf + base + tid * 4) = make_float4(x[0], x[1], x[2], x[3]);
  }
}

// ---------------------------------------------------------------- launch
extern "C" void kernel_launch(void* const* d_in, const int* in_sizes, int n_in,
                              void* d_out, int out_size, void* d_ws, size_t ws_size,
                              hipStream_t stream) {
  const float* query    = (const float*)d_in[0];
  const float* key_in   = (const float*)d_in[1];
  const float* value_in = (const float*)d_in[2];
  const float* mask     = (const float*)d_in[3];
  const float* Wq = (const float*)d_in[4];  const float* bq = (const float*)d_in[5];
  const float* Wk = (const float*)d_in[6];  const float* bk = (const float*)d_in[7];
  const float* Wv = (const float*)d_in[8];  const float* bv = (const float*)d_in[9];
  const float* Wo = (const float*)d_in[10]; const float* bo = (const float*)d_in[11];
  const float* ln1g = (const float*)d_in[12]; const float* ln1b = (const float*)d_in[13];
  const float* Wi = (const float*)d_in[14]; const float* bi = (const float*)d_in[15];
  const float* Wd = (const float*)d_in[16]; const float* bd = (const float*)d_in[17];
  const float* ln2g = (const float*)d_in[18]; const float* ln2b = (const float*)d_in[19];

  char* ws = (char*)d_ws;
  const size_t MB = 1ull << 20;
  if (ws_size < 112 * MB) return;

  __bf16* xq   = (__bf16*)(ws + 0 * MB);
  __bf16* xk   = (__bf16*)(ws + 8 * MB);
  __bf16* xv   = (__bf16*)(ws + 16 * MB);
  __bf16* x1b  = (__bf16*)(ws + 16 * MB);
  __bf16* qb   = (__bf16*)(ws + 24 * MB);
  __bf16* inter= (__bf16*)(ws + 24 * MB);
  __bf16* kb   = (__bf16*)(ws + 32 * MB);
  __bf16* alinb= (__bf16*)(ws + 40 * MB);
  __bf16* vt   = (__bf16*)(ws + 48 * MB);
  __bf16* ctxb = (__bf16*)(ws + 56 * MB);
  __bf16* ffb  = (__bf16*)(ws + 56 * MB);
  float*  mask2= (float*)(ws + 72 * MB);    // pre-scaled mask (16 KB)
  __bf16* wqt  = (__bf16*)(ws + 88 * MB);
  __bf16* wkt  = (__bf16*)(ws + 90 * MB);
  __bf16* wvt  = (__bf16*)(ws + 92 * MB);
  __bf16* wot  = (__bf16*)(ws + 94 * MB);
  __bf16* wit  = (__bf16*)(ws + 96 * MB);
  __bf16* wdt  = (__bf16*)(ws + 104 * MB);

  dim3 b256(256);

  PrepArgs pa;
  pa.win[0] = Wq; pa.win[1] = Wk; pa.win[2] = Wv; pa.win[3] = Wo;
  pa.win[4] = Wi; pa.win[5] = Wd;
  pa.wout[0] = wqt; pa.wout[1] = wkt; pa.wout[2] = wvt; pa.wout[3] = wot;
  pa.wout[4] = wit; pa.wout[5] = wdt;
  pa.cin[0] = query; pa.cin[1] = key_in; pa.cin[2] = value_in;
  pa.cout[0] = xq;   pa.cout[1] = xk;    pa.cout[2] = xv;
  pa.min = mask; pa.mout = mask2;
  prep_kernel<<<dim3(24580), b256, 0, stream>>>(pa);

  QKVArgs qa;
  qa.A[0] = xq;  qa.A[1] = xk;  qa.A[2] = xv;
  qa.Bt[0] = wqt; qa.Bt[1] = wkt; qa.Bt[2] = wvt;
  qa.bias[0] = bq; qa.bias[1] = bk; qa.bias[2] = bv;
  qa.out[0] = qb; qa.out[1] = kb; qa.out[2] = vt;   // V -> transposed direct
  qkv256_kernel<<<dim3(D_ / 256, M_ / 256, 3), dim3(512), 131072, stream>>>(qa, D_, D_);

  attn_kernel<<<dim3(S_ / 128, B_ * H_), dim3(512), 0, stream>>>(qb, kb, vt, mask2, ctxb);

  // Wo: 64x64 tiles, 1024 blocks (4/CU)
  gemm_kernel<4, 64, 64><<<dim3(D_ / 64, M_ / 64), b256, 0, stream>>>(ctxb, wot, bo, xq, (void*)alinb, D_, D_);

  ln_kernel<true><<<dim3(M_), b256, 0, stream>>>(alinb, ln1g, ln1b, nullptr, x1b);

  gemm256_kernel<2><<<dim3(DFF_ / 256, M_ / 256), dim3(512), 131072, stream>>>(x1b, wit, bi, (void*)inter, DFF_, D_);

  // Wd: 64x64 tiles, 1024 blocks (4/CU)
  gemm_kernel<4, 64, 64><<<dim3(D_ / 64, M_ / 64), b256, 0, stream>>>(inter, wdt, bd, x1b, (void*)ffb, D_, DFF_);

  ln_kernel<false><<<dim3(M_), b256, 0, stream>>>(ffb, ln2g, ln2b, (float*)d_out, nullptr);
}